// Round 9
// baseline (279.986 us; speedup 1.0000x reference)
//
#include <hip/hip_runtime.h>
#include <math.h>

typedef unsigned short u16;
using bf16x8 = __attribute__((ext_vector_type(8))) short;
using f32x4  = __attribute__((ext_vector_type(4))) float;

#define NS      128
#define NBLOCKS 4096    // 1 ray per block, 512 threads (8 waves)
#define NSLICE  17      // 13 (W1, slot-major K=416) + 4 (W2) slices of 4096 u16

// LDS pool (u16): 6-slot ring x 4096 u16 = 48 KB -> 3 blocks/CU.
// GEMM1 slice j lives at slot j%6 (2-slice phases keep build-ahead <= 4).
// h1 overlays slots 0..3 (drain barrier first), h2 re-overlays 0..3 after
// GEMM2's reads are drained.
#define POOLSZ 24576

// Raw barrier: drain LDS only; global register-prefetches stay in flight.
#define BAR() do { asm volatile("s_waitcnt lgkmcnt(0)" ::: "memory");        \
                   __builtin_amdgcn_s_barrier();                              \
                   asm volatile("" ::: "memory"); } while (0)

#define MF(A,B,C) __builtin_amdgcn_mfma_f32_16x16x32_bf16((A),(B),(C),0,0,0)

__device__ __forceinline__ u16 f2bf(float f) {           // host-prep path only
    unsigned int i = __float_as_uint(f);
    return (u16)((i + 0x7FFFu + ((i >> 16) & 1u)) >> 16);  // RNE
}

// pack two floats to bf16 pair [hi:lo] in one dword (single VALU op, RNE)
__device__ __forceinline__ unsigned pk(float hi, float lo) {
    unsigned r;
    asm("v_cvt_pk_bf16_f32 %0, %1, %2" : "=v"(r) : "v"(lo), "v"(hi));
    return r;
}
__device__ __forceinline__ u16 f2bf1(float f) {
    return (u16)((__float_as_uint(f) + 0x8000u) >> 16);
}

// Swizzled A-frag offset into the h region (k-slice kk -> ring slot kk,
// slots 0..3): XOR (k>>3)&3 into the chunk index (readers apply chunk^quad)
// to spread column-wise u16 epilogue writes across banks.
__device__ __forceinline__ int afoff_h(int m, int k) {
    int e = (k >> 3) & 3;
    int chunk = (m >> 4) * 64 + e * 16 + (m & 15);
    return (k >> 5) * 4096 + (chunk ^ e) * 8 + (k & 7);
}

// channel/slot -> original mlp_in k index (reference ordering).
// slot: 0 = value, 1..6 = sin f0..f5, 7..12 = cos f0..f5.
__device__ __forceinline__ int orig_k(int ch, int slot) {
    if (ch < 27) {
        if (slot == 0) return ch;
        if (slot <= 6) return 30 + ch * 6 + (slot - 1);     // sin(app)
        return 192 + ch * 6 + (slot - 7);                    // cos(app)
    } else {
        int c = ch - 27;
        if (slot == 0) return 27 + c;
        if (slot <= 6) return 354 + c * 6 + (slot - 1);      // sin(view)
        return 372 + c * 6 + (slot - 7);                     // cos(view)
    }
}

// GEMM1 slice j (consumption order) holds slot cons(j): chain order
// 0; s0,c0; s1,c1; ... s5,c5.
__device__ __forceinline__ int cons_slot(int j) {
    if (j == 0) return 0;
    return (j & 1) ? (j + 1) / 2 : 6 + j / 2;   // odd j -> sin, even -> cos
}

// W1 -> 13 slot-major slices (k = slot*32 + ch, permuted to chain order),
// W2 -> 4 slices at 53248, W3 -> 4 mini B-frag slices at 69632 (N pad 16)
__global__ __launch_bounds__(256) void prep_kernel(
    const float* __restrict__ W1, const float* __restrict__ W2,
    const float* __restrict__ W3, u16* __restrict__ ws)
{
    int idx = blockIdx.x * 256 + threadIdx.x;
    if (idx < 53248) {                               // W1r: [j13][nt8][lane64][jj8]
        int jj = idx & 7, lane = (idx >> 3) & 63, nt = (idx >> 9) & 7, j = idx >> 12;
        int q = lane >> 4, l15 = lane & 15;
        int ch = q * 8 + jj;                         // k_local = channel (0..31)
        int n = nt * 16 + l15;
        ws[idx] = (ch < 30) ? f2bf(W1[orig_k(ch, cons_slot(j)) * 128 + n]) : (u16)0;
    } else if (idx < 69632) {                        // W2r: [ks4][nt8][lane64][jj8]
        int i2 = idx - 53248;
        int jj = i2 & 7, lane = (i2 >> 3) & 63, nt = (i2 >> 9) & 7, ks = i2 >> 12;
        int k = ks * 32 + (lane >> 4) * 8 + jj;
        int n = nt * 16 + (lane & 15);
        ws[idx] = f2bf(W2[k * 128 + n]);
    } else if (idx < 71680) {                        // W3r: [ks4][lane64][jj8]
        int i3 = idx - 69632;
        int jj = i3 & 7, lane = (i3 >> 3) & 63, ks = i3 >> 9;
        int k = ks * 32 + (lane >> 4) * 8 + jj;
        int n = lane & 15;
        ws[idx] = (n < 3) ? f2bf(W3[k * 3 + n]) : (u16)0;
    }
}

// Load one slice's 2 B-frags (wave's 32-col strip) into named registers.
#define LOADB2(N0, N1, s)                                                     \
    if ((s) < NSLICE) {                                                       \
        const u16* wp = wp0 + (s) * 4096;                                     \
        N0 = *(const bf16x8*)(wp);                                            \
        N1 = *(const bf16x8*)(wp + 512);                                      \
    }

// One X-sourced K-slice: 4 A ds_reads (64-row strip, split 2+2) + 8 MFMA.
// Loads slice s+1's B-frags (2-pair ping-pong P,Q -> only 16 B-regs).
#define BODYX(s, C0,C1, N0,N1)                                                \
  {                                                                           \
    LOADB2(N0, N1, (s)+1);                                                    \
    const u16* ab = pool + ((s)%6)*4096 + (wm*256 + lane)*8;                  \
    bf16x8 a0 = *(const bf16x8*)(ab);                                         \
    bf16x8 a1 = *(const bf16x8*)(ab + 512);                                   \
    __builtin_amdgcn_s_setprio(1);                                            \
    acc[0][0]=MF(a0,C0,acc[0][0]); acc[0][1]=MF(a0,C1,acc[0][1]);             \
    acc[1][0]=MF(a1,C0,acc[1][0]); acc[1][1]=MF(a1,C1,acc[1][1]);             \
    a0 = *(const bf16x8*)(ab + 1024);                                         \
    a1 = *(const bf16x8*)(ab + 1536);                                         \
    acc[2][0]=MF(a0,C0,acc[2][0]); acc[2][1]=MF(a0,C1,acc[2][1]);             \
    acc[3][0]=MF(a1,C0,acc[3][0]); acc[3][1]=MF(a1,C1,acc[3][1]);             \
    __builtin_amdgcn_s_setprio(0);                                            \
  }

// One h-sourced K-slice (GEMM2, s = 13..16): A from swizzled h1 slots 0..3.
#define BODYH(s, C0,C1, N0,N1)                                                \
  {                                                                           \
    LOADB2(N0, N1, (s)+1);                                                    \
    int cb = ((s)-13) * 512 + ((wm*256 + lane) ^ quad);                       \
    bf16x8 a0 = *(const bf16x8*)(pool + cb*8);                                \
    bf16x8 a1 = *(const bf16x8*)(pool + (cb+64)*8);                           \
    __builtin_amdgcn_s_setprio(1);                                            \
    acc[0][0]=MF(a0,C0,acc[0][0]); acc[0][1]=MF(a0,C1,acc[0][1]);             \
    acc[1][0]=MF(a1,C0,acc[1][0]); acc[1][1]=MF(a1,C1,acc[1][1]);             \
    a0 = *(const bf16x8*)(pool + (cb+128)*8);                                 \
    a1 = *(const bf16x8*)(pool + (cb+192)*8);                                 \
    acc[2][0]=MF(a0,C0,acc[2][0]); acc[2][1]=MF(a0,C1,acc[2][1]);             \
    acc[3][0]=MF(a1,C0,acc[3][0]); acc[3][1]=MF(a1,C1,acc[3][1]);             \
    __builtin_amdgcn_s_setprio(0);                                            \
  }

// Write one slice's 8-channel strip (16B contiguous = one A-frag k-octet).
#define W8(j, A)                                                              \
  { uint4 w_; w_.x = pk(A[1],A[0]); w_.y = pk(A[3],A[2]);                     \
    w_.z = pk(A[5],A[4]); w_.w = pk(A[7],A[6]);                               \
    *(uint4*)(pool + ((j)%6)*4096 + bx2) = w_; }

// One doubling step for the 8 channel chains + write slices 1+2d (sin) and
// 2+2d (cos) into their ring slots.
#define DBL(d)                                                                \
  { _Pragma("unroll")                                                         \
    for (int i_ = 0; i_ < 8; ++i_) {                                          \
        float t_ = sreg[i_] * creg[i_];                                       \
        float u_ = creg[i_] * creg[i_] - sreg[i_] * sreg[i_];                 \
        sreg[i_] = t_ + t_; creg[i_] = u_;                                    \
    }                                                                         \
    W8(1 + 2*(d), sreg); W8(2 + 2*(d), creg); }

// 8 waves: wave (wm = wave>>2, wn = wave&3) owns a 64x32 output tile.
// (512,6): cap 85 unified regs (arch ~48 + 32 acc AGPR) -> 3 blocks/CU.
// Barriers only sync within a block; 3 resident blocks fill each other's
// barrier slack -- the latency the r7/r8 2-block structure couldn't hide.
__global__ __launch_bounds__(512, 6) void render_kernel(
    const float* __restrict__ sigma_g, const float* __restrict__ app_g,
    const float* __restrict__ view_g,  const float* __restrict__ dists_g,
    const float* __restrict__ b1_g,    const float* __restrict__ b2_g,
    const float* __restrict__ b3_g,    const u16* __restrict__ ws,
    float* __restrict__ out_g)
{
    __shared__ __align__(16) u16 pool[POOLSZ];
    __shared__ __align__(16) float part[NS * 3];
    __shared__ float scanS;          // wave0 scan total broadcast
    __shared__ float sum2[6];        // per-wave final partials

    const int tid  = threadIdx.x;
    const int lane = tid & 63;
    const int wave = tid >> 6;       // 0..7
    const int l15  = lane & 15;
    const int quad = lane >> 4;
    const int wm   = wave >> 2;      // row half (64 rows)
    const int wn   = wave & 3;       // col quarter (32 cols)

    const int r  = blockIdx.x;
    const int rb = r * NS;
    const int row = tid & 127;       // X-build row (all 512 threads build)
    const int g   = tid >> 7;        // X-build channel group (8 channels)
    const float* ap = app_g  + (rb + row) * 27;
    const float* vp = view_g + (rb + row) * 3;
    // per-thread build offset within a slice: channels 8g..8g+7 of this row
    const int bx2 = ((row >> 4) * 64 + g * 16 + (row & 15)) * 8;

    // issue B load for slice 0 ASAP (2-pair ping-pong P,Q)
    const u16* wp0 = ws + (wn * 128 + lane) * 8;
    bf16x8 bP0, bP1, bQ0, bQ1;
    LOADB2(bP0, bP1, 0);

    // load this thread's 8 channel inputs (30 real, 2 pad)
    float v8[8];
    #pragma unroll
    for (int i = 0; i < 8; ++i) {
        int ch = g * 8 + i;
        v8[i] = (ch < 27) ? ap[ch] : ((ch < 30) ? vp[ch - 27] : 0.f);
    }

    // ---- alpha + shuffle transmittance scan (waves 0,1) ----
    float alpha = 0.f, prod = 1.f, wr = 0.f;
    if (tid < NS) {
        float x  = sigma_g[rb + tid] - 10.f;
        float sp = (x > 20.f) ? x : log1pf(expf(x));
        alpha = 1.f - expf(-sp * dists_g[rb + tid] * 25.f);
        if (tid == NS - 1) alpha = 1.f;
        float tb = 1.f - alpha + 1e-10f;
        prod = tb;
        #pragma unroll
        for (int d = 1; d < 64; d <<= 1) {
            float v = __shfl_up(prod, d);
            if (lane >= d) prod *= v;
        }
        if (tid == 63) scanS = prod;
    }

    // ---- chain start: sincos; write slices 0,1,2 -> slots 0,1,2 ----
    float sreg[8], creg[8];
    #pragma unroll
    for (int i = 0; i < 8; ++i) {
        float rev = v8[i] * 0.15915494309189535f;
        rev -= floorf(rev);
        sreg[i] = __builtin_amdgcn_sinf(rev);
        creg[i] = __builtin_amdgcn_cosf(rev);
    }
    W8(0, v8); W8(1, sreg); W8(2, creg);
    BAR();                                   // #1

    // finish weights: wr = alpha * T_exclusive
    if (tid < NS) {
        float prev = __shfl_up(prod, 1);
        float base = (lane == 0) ? 1.f : prev;
        float scale = (wave == 1) ? scanS : 1.f;
        wr = alpha * base * scale;
    }

    const f32x4 vzero = {0.f, 0.f, 0.f, 0.f};
    f32x4 acc[4][2];
    #pragma unroll
    for (int mt = 0; mt < 4; ++mt)
        #pragma unroll
        for (int nt = 0; nt < 2; ++nt) acc[mt][nt] = vzero;

    // ---- GEMM1: 13 slices, 2-slice phases on the 6-slot ring ----
    // phase A: reads slots 0,1; builds slices 3,4 -> slots 3,4
    BODYX(0,  bP0,bP1, bQ0,bQ1);
    BODYX(1,  bQ0,bQ1, bP0,bP1);
    DBL(1);  BAR();                          // #2
    // phase B: reads 2,3; builds 5,6 -> slots 5,0 (slot0 drained at #2)
    BODYX(2,  bP0,bP1, bQ0,bQ1);
    BODYX(3,  bQ0,bQ1, bP0,bP1);
    DBL(2);  BAR();                          // #3
    // phase C: reads 4,5; builds 7,8 -> slots 1,2 (drained #2/#3)
    BODYX(4,  bP0,bP1, bQ0,bQ1);
    BODYX(5,  bQ0,bQ1, bP0,bP1);
    DBL(3);  BAR();                          // #4
    // phase D: reads 0,1 (slices 6,7); builds 9,10 -> slots 3,4 (drained #3/#4)
    BODYX(6,  bP0,bP1, bQ0,bQ1);
    BODYX(7,  bQ0,bQ1, bP0,bP1);
    DBL(4);  BAR();                          // #5
    // phase E: reads 2,3 (slices 8,9); builds 11,12 -> slots 5,0 (drained #4/#5)
    BODYX(8,  bP0,bP1, bQ0,bQ1);
    BODYX(9,  bQ0,bQ1, bP0,bP1);
    DBL(5);  BAR();                          // #6
    // phase F: reads 4,5,0 (slices 10,11,12); b1 latency hides here
    BODYX(10, bP0,bP1, bQ0,bQ1);
    BODYX(11, bQ0,bQ1, bP0,bP1);
    const float b1r0 = b1_g[wn * 32 + l15];
    const float b1r1 = b1_g[wn * 32 + 16 + l15];
    BODYX(12, bP0,bP1, bQ0,bQ1);             // loads slice 13 -> Q
    BAR();                                   // #7: drain F reads pre-h1

    // ---- epilogue 1: h1 = relu(acc + b1) -> slots 0..3 ----
    #pragma unroll
    for (int mt = 0; mt < 4; ++mt)
        #pragma unroll
        for (int nt = 0; nt < 2; ++nt) {
            int col = wn * 32 + nt * 16 + l15;
            #pragma unroll
            for (int rr = 0; rr < 4; ++rr) {
                int rw = wm * 64 + mt * 16 + quad * 4 + rr;
                pool[afoff_h(rw, col)] =
                    f2bf1(fmaxf(acc[mt][nt][rr] + ((nt == 0) ? b1r0 : b1r1), 0.f));
            }
            acc[mt][nt] = vzero;          // reset for GEMM2
        }
    BAR();                                   // #8: h1 visible

    const float b2r0 = b2_g[wn * 32 + l15];
    const float b2r1 = b2_g[wn * 32 + 16 + l15];

    // ---- GEMM2: slices 13..16 (h1 @ W2), barrier-free run ----
    BODYH(13, bQ0,bQ1, bP0,bP1);             // loads slice 14 -> P
    BODYH(14, bP0,bP1, bQ0,bQ1);             // loads slice 15 -> Q
    BODYH(15, bQ0,bQ1, bP0,bP1);             // loads slice 16 -> P
    BODYH(16, bP0,bP1, bQ0,bQ1);             // load guard kills slice 17
    BAR();                                   // #9: drain GEMM2 h1 reads

    // ---- epilogue 2: h2 = relu(acc + b2) -> slots 0..3 (overwrite h1) ----
    #pragma unroll
    for (int mt = 0; mt < 4; ++mt)
        #pragma unroll
        for (int nt = 0; nt < 2; ++nt) {
            int col = wn * 32 + nt * 16 + l15;
            #pragma unroll
            for (int rr = 0; rr < 4; ++rr) {
                int rw = wm * 64 + mt * 16 + quad * 4 + rr;
                pool[afoff_h(rw, col)] =
                    f2bf1(fmaxf(acc[mt][nt][rr] + ((nt == 0) ? b2r0 : b2r1), 0.f));
            }
        }
    BAR();                                   // #10: h2 visible

    // ---- layer 3 via MFMA: rgb = sigmoid(h2 @ W3 + b3); wave = row-tile ----
    const u16* w3r = ws + 69632;
    const float b3v = (l15 < 3) ? b3_g[l15] : 0.f;
    f32x4 acc3 = vzero;
    #pragma unroll
    for (int ks = 0; ks < 4; ++ks) {
        bf16x8 w3f = *(const bf16x8*)(w3r + (ks * 64 + lane) * 8);
        int c = ks * 512 + ((wave * 64 + lane) ^ quad);
        bf16x8 a3 = *(const bf16x8*)(pool + c * 8);
        acc3 = MF(a3, w3f, acc3);
    }
    if (l15 < 3) {
        #pragma unroll
        for (int rr = 0; rr < 4; ++rr) {
            int rw = wave * 16 + quad * 4 + rr;
            float v = acc3[rr] + b3v;
            part[rw * 3 + l15] = 1.f / (1.f + expf(-v));
        }
    }
    BAR();                                   // #11

    // ---- weighted sum over samples ----
    if (tid < NS) {
        float v0 = wr * part[tid * 3 + 0];
        float v1 = wr * part[tid * 3 + 1];
        float v2 = wr * part[tid * 3 + 2];
        #pragma unroll
        for (int d = 1; d < 64; d <<= 1) {
            v0 += __shfl_xor(v0, d);
            v1 += __shfl_xor(v1, d);
            v2 += __shfl_xor(v2, d);
        }
        if (lane == 0) {
            sum2[wave * 3 + 0] = v0;
            sum2[wave * 3 + 1] = v1;
            sum2[wave * 3 + 2] = v2;
        }
    }
    BAR();                                   // #12
    if (tid == 0) {
        out_g[r * 3 + 0] = sum2[0] + sum2[3];
        out_g[r * 3 + 1] = sum2[1] + sum2[4];
        out_g[r * 3 + 2] = sum2[2] + sum2[5];
    }
}

extern "C" void kernel_launch(void* const* d_in, const int* in_sizes, int n_in,
                              void* d_out, int out_size, void* d_ws, size_t ws_size,
                              hipStream_t stream) {
    (void)in_sizes; (void)n_in; (void)out_size; (void)ws_size;
    const float* sigma = (const float*)d_in[0];
    const float* app   = (const float*)d_in[1];
    const float* view  = (const float*)d_in[2];
    const float* dists = (const float*)d_in[3];
    const float* W1    = (const float*)d_in[4];
    const float* b1    = (const float*)d_in[5];
    const float* W2    = (const float*)d_in[6];
    const float* b2    = (const float*)d_in[7];
    const float* W3    = (const float*)d_in[8];
    const float* b3    = (const float*)d_in[9];
    float* out = (float*)d_out;

    u16* ws = (u16*)d_ws;   // 53248 (W1r) + 16384 (W2r) + 2048 (W3r) u16 = 143360 B

    prep_kernel<<<280, 256, 0, stream>>>(W1, W2, W3, ws);
    render_kernel<<<NBLOCKS, 512, 0, stream>>>(sigma, app, view, dists,
                                               b1, b2, b3, ws, out);
}

// Round 10
// 210.319 us; speedup vs baseline: 1.3312x; 1.3312x over previous
//
#include <hip/hip_runtime.h>
#include <math.h>

typedef unsigned short u16;
using bf16x8 = __attribute__((ext_vector_type(8))) short;
using f32x4  = __attribute__((ext_vector_type(4))) float;

#define NS      128
#define NBLOCKS 8192    // 2 blocks per ray (64 samples each), 256 threads
#define NSLICE  19      // 15 (W1, 16-slot channel-major) + 4 (W2) slices

// LDS pool (u16): 6-slot ring x 2048 u16 = 24 KB (64-row slices).
// X slice j (j=0..14) lives at slot j%6. h1/h2 overlay slots 0..3
// (4 k-slices x 2048). 4-wave blocks at natural regs (~90) -> 5 blocks/CU.
#define POOLSZ 12288

// Raw barrier: drain LDS only; global register-prefetches stay in flight.
#define BAR() do { asm volatile("s_waitcnt lgkmcnt(0)" ::: "memory");        \
                   __builtin_amdgcn_s_barrier();                              \
                   asm volatile("" ::: "memory"); } while (0)

#define MF(A,B,C) __builtin_amdgcn_mfma_f32_16x16x32_bf16((A),(B),(C),0,0,0)

__device__ __forceinline__ u16 f2bf(float f) {           // host-prep path only
    unsigned int i = __float_as_uint(f);
    return (u16)((i + 0x7FFFu + ((i >> 16) & 1u)) >> 16);  // RNE
}

// pack two floats to bf16 pair [hi:lo] in one dword (single VALU op, RNE)
__device__ __forceinline__ unsigned pk(float hi, float lo) {
    unsigned r;
    asm("v_cvt_pk_bf16_f32 %0, %1, %2" : "=v"(r) : "v"(lo), "v"(hi));
    return r;
}
__device__ __forceinline__ u16 f2bf1(float f) {
    return (u16)((__float_as_uint(f) + 0x8000u) >> 16);
}

// Swizzled A-frag offset into the h region (k-slice kk -> ring slot kk,
// slots 0..3; [64x32] A-frag order per slot): XOR (k>>3)&3 into the chunk
// index (readers apply chunk^quad) to spread column-wise u16 writes.
__device__ __forceinline__ int afoff_h(int m, int k) {
    int e = (k >> 3) & 3;
    int chunk = (m >> 4) * 64 + e * 16 + (m & 15);
    return (k >> 5) * 2048 + (chunk ^ e) * 8 + (k & 7);
}

// channel/slot -> original mlp_in k index (reference ordering)
__device__ __forceinline__ int orig_k(int ch, int slot) {
    if (ch < 27) {
        if (slot == 0) return ch;
        if (slot <= 6) return 30 + ch * 6 + (slot - 1);     // sin(app)
        return 192 + ch * 6 + (slot - 7);                    // cos(app)
    } else {
        int c = ch - 27;
        if (slot == 0) return 27 + c;
        if (slot <= 6) return 354 + c * 6 + (slot - 1);      // sin(view)
        return 372 + c * 6 + (slot - 7);                     // cos(view)
    }
}

__device__ __forceinline__ float ldch(const float* ap, const float* vp, int c) {
    return (c < 27) ? ap[c] : vp[c - 27];
}

// build one channel-half of a frag-order X slice at a precomputed dst:
// slots [v, sin f0..5, cos f0..5, 0 x3] as two 16B chunks (dst, dst+128).
__device__ __forceinline__ void build_x(u16* dst, float v) {
    float rev = v * 0.15915494309189535f;
    rev -= floorf(rev);
    float s0 = __builtin_amdgcn_sinf(rev);
    float c0 = __builtin_amdgcn_cosf(rev);
    float s1 = 2.f * s0 * c0, c1 = c0 * c0 - s0 * s0;
    float s2 = 2.f * s1 * c1, c2 = c1 * c1 - s1 * s1;
    float s3 = 2.f * s2 * c2, c3 = c2 * c2 - s2 * s2;
    float s4 = 2.f * s3 * c3, c4 = c3 * c3 - s3 * s3;
    float s5 = 2.f * s4 * c4, c5 = c4 * c4 - s4 * s4;
    uint4 lo, hi;
    lo.x = pk(s0, v);  lo.y = pk(s2, s1);  lo.z = pk(s4, s3);  lo.w = pk(c0, s5);
    hi.x = pk(c2, c1); hi.y = pk(c4, c3);  hi.z = pk(0.f, c5); hi.w = 0u;
    *(uint4*)(dst)       = lo;
    *(uint4*)(dst + 128) = hi;
}

// W1 -> 15 slices, W2 -> 4 slices at 61440, W3 -> 4 mini slices at 77824;
// also zeroes the output (render halves atomicAdd into it).
__global__ __launch_bounds__(256) void prep_kernel(
    const float* __restrict__ W1, const float* __restrict__ W2,
    const float* __restrict__ W3, u16* __restrict__ ws,
    float* __restrict__ out)
{
    int idx = blockIdx.x * 256 + threadIdx.x;
    if (idx < 12288) out[idx] = 0.f;                 // 4096 rays x 3
    if (idx < 61440) {                               // W1r: [ks15][nt8][lane64][j8]
        int j = idx & 7, lane = (idx >> 3) & 63, nt = (idx >> 9) & 7, ks = idx >> 12;
        int q = lane >> 4, l15 = lane & 15;
        int klocal = q * 8 + j;                      // 0..31
        int ch = ks * 2 + (klocal >> 4);
        int slot = klocal & 15;
        int n = nt * 16 + l15;
        ws[idx] = (slot < 13) ? f2bf(W1[orig_k(ch, slot) * 128 + n]) : (u16)0;
    } else if (idx < 77824) {                        // W2r: [ks4][nt8][lane64][j8]
        int i2 = idx - 61440;
        int j = i2 & 7, lane = (i2 >> 3) & 63, nt = (i2 >> 9) & 7, ks = i2 >> 12;
        int k = ks * 32 + (lane >> 4) * 8 + j;
        int n = nt * 16 + (lane & 15);
        ws[idx] = f2bf(W2[k * 128 + n]);
    } else if (idx < 79872) {                        // W3r: [ks4][lane64][j8], N pad 16
        int i3 = idx - 77824;
        int j = i3 & 7, lane = (i3 >> 3) & 63, ks = i3 >> 9;
        int k = ks * 32 + (lane >> 4) * 8 + j;
        int n = lane & 15;
        ws[idx] = (n < 3) ? f2bf(W3[k * 3 + n]) : (u16)0;
    }
}

// Load one slice's 4 B-frags (wave's 64-col strip) into named registers.
#define LOADB4(N0,N1,N2,N3, s)                                                \
    if ((s) < NSLICE) {                                                       \
        const u16* wp = wp0 + (s) * 4096;                                     \
        N0 = *(const bf16x8*)(wp);                                            \
        N1 = *(const bf16x8*)(wp + 512);                                      \
        N2 = *(const bf16x8*)(wp + 1024);                                     \
        N3 = *(const bf16x8*)(wp + 1536);                                     \
    }

// One X-sourced K-slice: 2 A ds_reads (32-row wave strip) + 8 MFMA.
// Loads slice s+1's B-frags (ping-pong: slice s uses P if s even).
#define BODYX(s, C0,C1,C2,C3, N0,N1,N2,N3)                                    \
  {                                                                           \
    LOADB4(N0,N1,N2,N3, (s)+1);                                               \
    const u16* ab = pool + ((s)%6)*2048 + (wm*128 + lane)*8;                  \
    bf16x8 a0 = *(const bf16x8*)(ab);                                         \
    bf16x8 a1 = *(const bf16x8*)(ab + 512);                                   \
    __builtin_amdgcn_s_setprio(1);                                            \
    acc[0][0]=MF(a0,C0,acc[0][0]); acc[0][1]=MF(a0,C1,acc[0][1]);             \
    acc[0][2]=MF(a0,C2,acc[0][2]); acc[0][3]=MF(a0,C3,acc[0][3]);             \
    acc[1][0]=MF(a1,C0,acc[1][0]); acc[1][1]=MF(a1,C1,acc[1][1]);             \
    acc[1][2]=MF(a1,C2,acc[1][2]); acc[1][3]=MF(a1,C3,acc[1][3]);             \
    __builtin_amdgcn_s_setprio(0);                                            \
  }

// One h-sourced K-slice (GEMM2, s = 15..18): A from swizzled h1 slots 0..3.
#define BODYH(s, C0,C1,C2,C3, N0,N1,N2,N3)                                    \
  {                                                                           \
    LOADB4(N0,N1,N2,N3, (s)+1);                                               \
    int cb = ((s)-15)*256 + ((wm*128 + lane) ^ quad);                         \
    bf16x8 a0 = *(const bf16x8*)(pool + cb*8);                                \
    bf16x8 a1 = *(const bf16x8*)(pool + (cb+64)*8);                           \
    __builtin_amdgcn_s_setprio(1);                                            \
    acc[0][0]=MF(a0,C0,acc[0][0]); acc[0][1]=MF(a0,C1,acc[0][1]);             \
    acc[0][2]=MF(a0,C2,acc[0][2]); acc[0][3]=MF(a0,C3,acc[0][3]);             \
    acc[1][0]=MF(a1,C0,acc[1][0]); acc[1][1]=MF(a1,C1,acc[1][1]);             \
    acc[1][2]=MF(a1,C2,acc[1][2]); acc[1][3]=MF(a1,C3,acc[1][3]);             \
    __builtin_amdgcn_s_setprio(0);                                            \
  }

// Build group g (slices 2g, 2g+1; channels 4g..4g+3): thread builds slice
// 2g+(cl>>1), channel-half cl&1. Roll the 2-deep input prefetch, barrier.
#define GENDB(g)                                                              \
  {                                                                           \
    if (4*(g) + cl < 30)                                                      \
        build_x(pool + ((2*(g) + (cl>>1)) % 6) * 2048 + bxoff, pv_cur);       \
    pv_cur = pv_nxt;                                                          \
    if (4*((g)+2) + cl < 30) pv_nxt = ldch(ap, vp, 4*((g)+2) + cl);           \
    BAR();                                                                    \
  }

// 4 waves: wave (wm = wave>>1, wn = wave&1) owns a 32x64 output tile of the
// block's 64x128 half-tile. acc 2x4 f32x4 = 32 AGPR, B ping-pong 32 VGPR.
// NO min-waves cap: natural alloc (~90 unified) -> 5 waves/SIMD -> 5 blocks.
__global__ __launch_bounds__(256) void render_kernel(
    const float* __restrict__ sigma_g, const float* __restrict__ app_g,
    const float* __restrict__ view_g,  const float* __restrict__ dists_g,
    const float* __restrict__ b1_g,    const float* __restrict__ b2_g,
    const float* __restrict__ b3_g,    const u16* __restrict__ ws,
    float* __restrict__ out_g)
{
    __shared__ __align__(16) u16 pool[POOLSZ];
    __shared__ __align__(16) float part[64 * 3];
    __shared__ float scanS;          // wave0 scan total broadcast

    const int tid  = threadIdx.x;
    const int lane = tid & 63;
    const int wave = tid >> 6;       // 0..3
    const int l15  = lane & 15;
    const int quad = lane >> 4;
    const int wm   = wave >> 1;      // row half of the 64-row tile (32 rows)
    const int wn   = wave & 1;       // col half (64 cols)

    const int r    = blockIdx.x >> 1;
    const int half = blockIdx.x & 1; // which 64-sample half of the ray
    const int rb   = r * NS;
    const int row  = tid & 63;       // X-build row (local sample)
    const int cl   = tid >> 6;       // X-build channel-local 0..3
    const float* ap = app_g  + (rb + half * 64 + row) * 27;
    const float* vp = view_g + (rb + half * 64 + row) * 3;
    // per-thread build offset within a slice
    const int bxoff = (row >> 4) * 512 + (((cl & 1) * 32) + (row & 15)) * 8;

    // issue B load for slice 0 ASAP (ping-pong P,Q; wave's 64-col strip)
    const u16* wp0 = ws + wn * 2048 + lane * 8;
    bf16x8 bP0, bP1, bP2, bP3, bQ0, bQ1, bQ2, bQ3;
    LOADB4(bP0, bP1, bP2, bP3, 0);

    // rolling input prefetch (2 resident)
    float pv_cur = ldch(ap, vp, cl);             // group 0
    float pv_nxt = ldch(ap, vp, 4 + cl);         // group 1

    // ---- alpha + shuffle transmittance scan over the FULL ray (waves 0,1) ----
    float alpha = 0.f, prod = 1.f, wr = 0.f;
    if (tid < NS) {
        float x  = sigma_g[rb + tid] - 10.f;
        float sp = (x > 20.f) ? x : log1pf(expf(x));
        alpha = 1.f - expf(-sp * dists_g[rb + tid] * 25.f);
        if (tid == NS - 1) alpha = 1.f;
        float tb = 1.f - alpha + 1e-10f;
        prod = tb;
        #pragma unroll
        for (int d = 1; d < 64; d <<= 1) {
            float v = __shfl_up(prod, d);
            if (lane >= d) prod *= v;
        }
        if (tid == 63) scanS = prod;
    }

    // ---- pre-build groups 0,1 (slices 0..3 -> slots 0..3) ----
    build_x(pool + ((cl >> 1)) * 2048 + bxoff, pv_cur);           // g0
    pv_cur = pv_nxt; pv_nxt = ldch(ap, vp, 8 + cl);               // g2
    build_x(pool + (2 + (cl >> 1)) * 2048 + bxoff, pv_cur);       // g1
    pv_cur = pv_nxt; pv_nxt = ldch(ap, vp, 12 + cl);              // g3
    BAR();                                   // #1

    // finish weights: wr = alpha * T_exclusive (global sample = tid)
    if (tid < NS) {
        float prev = __shfl_up(prod, 1);
        float base = (lane == 0) ? 1.f : prev;
        float scale = (wave == 1) ? scanS : 1.f;
        wr = alpha * base * scale;
    }

    const f32x4 vzero = {0.f, 0.f, 0.f, 0.f};
    f32x4 acc[2][4];
    #pragma unroll
    for (int mt = 0; mt < 2; ++mt)
        #pragma unroll
        for (int nt = 0; nt < 4; ++nt) acc[mt][nt] = vzero;

    // ---- GEMM1: 15 slices, 2-slice phases on the 6-slot ring ----
    // P0: reads slots 0,1; builds g2 -> slots 4,5 (fresh)
    BODYX(0,  bP0,bP1,bP2,bP3, bQ0,bQ1,bQ2,bQ3);
    BODYX(1,  bQ0,bQ1,bQ2,bQ3, bP0,bP1,bP2,bP3);
    GENDB(2);                                // #2
    // P1: reads 2,3; builds g3 -> slots 0,1 (drained #2)
    BODYX(2,  bP0,bP1,bP2,bP3, bQ0,bQ1,bQ2,bQ3);
    BODYX(3,  bQ0,bQ1,bQ2,bQ3, bP0,bP1,bP2,bP3);
    GENDB(3);                                // #3
    // P2: reads 4,5; builds g4 -> slots 2,3 (drained #3)
    BODYX(4,  bP0,bP1,bP2,bP3, bQ0,bQ1,bQ2,bQ3);
    BODYX(5,  bQ0,bQ1,bQ2,bQ3, bP0,bP1,bP2,bP3);
    GENDB(4);                                // #4
    // P3: reads 0,1 (slices 6,7); builds g5 -> slots 4,5 (drained #4)
    BODYX(6,  bP0,bP1,bP2,bP3, bQ0,bQ1,bQ2,bQ3);
    BODYX(7,  bQ0,bQ1,bQ2,bQ3, bP0,bP1,bP2,bP3);
    GENDB(5);                                // #5
    // P4: reads 2,3 (slices 8,9); builds g6 -> slots 0,1 (drained #5)
    BODYX(8,  bP0,bP1,bP2,bP3, bQ0,bQ1,bQ2,bQ3);
    BODYX(9,  bQ0,bQ1,bQ2,bQ3, bP0,bP1,bP2,bP3);
    GENDB(6);                                // #6
    // P5: reads 4,5 (slices 10,11); builds g7 (slice 14) -> slot 2 (drained #6)
    BODYX(10, bP0,bP1,bP2,bP3, bQ0,bQ1,bQ2,bQ3);
    BODYX(11, bQ0,bQ1,bQ2,bQ3, bP0,bP1,bP2,bP3);
    GENDB(7);                                // #7
    // P6: reads 0,1,2 (slices 12,13,14); b1 latency hides here
    BODYX(12, bP0,bP1,bP2,bP3, bQ0,bQ1,bQ2,bQ3);
    BODYX(13, bQ0,bQ1,bQ2,bQ3, bP0,bP1,bP2,bP3);
    float b1r[4];
    #pragma unroll
    for (int nt = 0; nt < 4; ++nt) b1r[nt] = b1_g[wn * 64 + nt * 16 + l15];
    BODYX(14, bP0,bP1,bP2,bP3, bQ0,bQ1,bQ2,bQ3);   // loads slice 15 -> Q
    BAR();                                   // #8: drain P6 reads pre-h1

    // ---- epilogue 1: h1 = relu(acc + b1) -> slots 0..3
    // (slot 3 last read P4, drained #6; slots 0,1,2 drained #8) ----
    #pragma unroll
    for (int mt = 0; mt < 2; ++mt)
        #pragma unroll
        for (int nt = 0; nt < 4; ++nt) {
            int col = wn * 64 + nt * 16 + l15;
            #pragma unroll
            for (int rr = 0; rr < 4; ++rr) {
                int rw = wm * 32 + mt * 16 + quad * 4 + rr;
                pool[afoff_h(rw, col)] =
                    f2bf1(fmaxf(acc[mt][nt][rr] + b1r[nt], 0.f));
            }
            acc[mt][nt] = vzero;          // reset for GEMM2
        }
    BAR();                                   // #9: h1 visible

    float b2r[4];
    #pragma unroll
    for (int nt = 0; nt < 4; ++nt) b2r[nt] = b2_g[wn * 64 + nt * 16 + l15];

    // ---- GEMM2: slices 15..18 (h1 @ W2), barrier-free run ----
    BODYH(15, bQ0,bQ1,bQ2,bQ3, bP0,bP1,bP2,bP3);   // loads 16 -> P
    BODYH(16, bP0,bP1,bP2,bP3, bQ0,bQ1,bQ2,bQ3);   // loads 17 -> Q
    BODYH(17, bQ0,bQ1,bQ2,bQ3, bP0,bP1,bP2,bP3);   // loads 18 -> P
    BODYH(18, bP0,bP1,bP2,bP3, bQ0,bQ1,bQ2,bQ3);   // guard kills 19
    BAR();                                   // #10: drain GEMM2 h1 reads

    // ---- epilogue 2: h2 = relu(acc + b2) -> slots 0..3 (overwrite h1) ----
    #pragma unroll
    for (int mt = 0; mt < 2; ++mt)
        #pragma unroll
        for (int nt = 0; nt < 4; ++nt) {
            int col = wn * 64 + nt * 16 + l15;
            #pragma unroll
            for (int rr = 0; rr < 4; ++rr) {
                int rw = wm * 32 + mt * 16 + quad * 4 + rr;
                pool[afoff_h(rw, col)] =
                    f2bf1(fmaxf(acc[mt][nt][rr] + b2r[nt], 0.f));
            }
        }
    BAR();                                   // #11: h2 visible

    // ---- layer 3 via MFMA: rgb = sigmoid(h2 @ W3 + b3); wave = 16-row tile ----
    const u16* w3r = ws + 77824;
    const float b3v = (l15 < 3) ? b3_g[l15] : 0.f;
    f32x4 acc3 = vzero;
    #pragma unroll
    for (int ks = 0; ks < 4; ++ks) {
        bf16x8 w3f = *(const bf16x8*)(w3r + (ks * 64 + lane) * 8);
        int c = ks * 256 + ((wave * 64 + lane) ^ quad);
        bf16x8 a3 = *(const bf16x8*)(pool + c * 8);
        acc3 = MF(a3, w3f, acc3);
    }
    if (l15 < 3) {
        #pragma unroll
        for (int rr = 0; rr < 4; ++rr) {
            int rw = wave * 16 + quad * 4 + rr;
            float v = acc3[rr] + b3v;
            part[rw * 3 + l15] = 1.f / (1.f + expf(-v));
        }
    }
    BAR();                                   // #12

    // ---- weighted sum over this half's samples; atomicAdd the partial ----
    if ((tid >> 6) == half) {        // exactly wave 'half': tid == global sample
        int local = tid & 63;
        float v0 = wr * part[local * 3 + 0];
        float v1 = wr * part[local * 3 + 1];
        float v2 = wr * part[local * 3 + 2];
        #pragma unroll
        for (int d = 1; d < 64; d <<= 1) {
            v0 += __shfl_xor(v0, d);
            v1 += __shfl_xor(v1, d);
            v2 += __shfl_xor(v2, d);
        }
        if (lane == 0) {
            atomicAdd(&out_g[r * 3 + 0], v0);
            atomicAdd(&out_g[r * 3 + 1], v1);
            atomicAdd(&out_g[r * 3 + 2], v2);
        }
    }
}

extern "C" void kernel_launch(void* const* d_in, const int* in_sizes, int n_in,
                              void* d_out, int out_size, void* d_ws, size_t ws_size,
                              hipStream_t stream) {
    (void)in_sizes; (void)n_in; (void)out_size; (void)ws_size;
    const float* sigma = (const float*)d_in[0];
    const float* app   = (const float*)d_in[1];
    const float* view  = (const float*)d_in[2];
    const float* dists = (const float*)d_in[3];
    const float* W1    = (const float*)d_in[4];
    const float* b1    = (const float*)d_in[5];
    const float* W2    = (const float*)d_in[6];
    const float* b2    = (const float*)d_in[7];
    const float* W3    = (const float*)d_in[8];
    const float* b3    = (const float*)d_in[9];
    float* out = (float*)d_out;

    u16* ws = (u16*)d_ws;   // 61440 (W1r) + 16384 (W2r) + 2048 (W3r) u16 = 159744 B

    prep_kernel<<<312, 256, 0, stream>>>(W1, W2, W3, ws, out);
    render_kernel<<<NBLOCKS, 256, 0, stream>>>(sigma, app, view, dists,
                                               b1, b2, b3, ws, out);
}

// Round 11
// 196.310 us; speedup vs baseline: 1.4262x; 1.0714x over previous
//
#include <hip/hip_runtime.h>
#include <math.h>

typedef unsigned short u16;
using bf16x8 = __attribute__((ext_vector_type(8))) short;
using f32x4  = __attribute__((ext_vector_type(4))) float;

#define NS      128
#define NBLOCKS 4096    // 1 ray per block, 512 threads (8 waves)
#define NSLICE  19      // 15 (W1) + 4 (W2) unified W slices of 4096 u16

// LDS pool (u16): X QUAD-buffer = 4 group slots x 8192 u16 = 64 KB.
// Slice s lives at (s&7)*4096. h1 overlays slots 0,1 (u16 0..16384);
// h2 overlays slots 2,3 (16384..32768) -> epilogue writes never race live
// readers, so no read-drain barriers. 7 barriers/ray total.
#define POOLSZ 32768
#define OH2    16384

// Raw barrier: drain LDS only; global register-prefetches stay in flight.
#define BAR() do { asm volatile("s_waitcnt lgkmcnt(0)" ::: "memory");        \
                   __builtin_amdgcn_s_barrier();                              \
                   asm volatile("" ::: "memory"); } while (0)

#define MF(A,B,C) __builtin_amdgcn_mfma_f32_16x16x32_bf16((A),(B),(C),0,0,0)

__device__ __forceinline__ u16 f2bf(float f) {           // host-prep path only
    unsigned int i = __float_as_uint(f);
    return (u16)((i + 0x7FFFu + ((i >> 16) & 1u)) >> 16);  // RNE
}

// pack two floats to bf16 pair [hi:lo] in one dword (single VALU op, RNE)
__device__ __forceinline__ unsigned pk(float hi, float lo) {
    unsigned r;
    asm("v_cvt_pk_bf16_f32 %0, %1, %2" : "=v"(r) : "v"(lo), "v"(hi));
    return r;
}

// Swizzled A-frag-order offset for a h [128x128] region: XOR (k>>3)&3 into
// the chunk index (readers apply chunk^quad) to spread the epilogue's
// column-wise u16 writes across more banks.
__device__ __forceinline__ int afoff_h(int m, int k) {
    int chunk = ((k >> 5) * 8 + (m >> 4)) * 64 + ((k >> 3) & 3) * 16 + (m & 15);
    chunk ^= (k >> 3) & 3;
    return chunk * 8 + (k & 7);
}

// channel/slot -> original mlp_in k index (reference ordering)
__device__ __forceinline__ int orig_k(int ch, int slot) {
    if (ch < 27) {
        if (slot == 0) return ch;
        if (slot <= 6) return 30 + ch * 6 + (slot - 1);     // sin(app)
        return 192 + ch * 6 + (slot - 7);                    // cos(app)
    } else {
        int c = ch - 27;
        if (slot == 0) return 27 + c;
        if (slot <= 6) return 354 + c * 6 + (slot - 1);      // sin(view)
        return 372 + c * 6 + (slot - 7);                     // cos(view)
    }
}

__device__ __forceinline__ float ldch(const float* ap, const float* vp, int c) {
    return (c < 27) ? ap[c] : vp[c - 27];
}

// build one channel-half of a frag-order X slice at a precomputed dst:
// slots [v, sin f0..5, cos f0..5, 0 x3] as two 16B chunks (dst, dst+128).
__device__ __forceinline__ void build_x(u16* dst, float v) {
    float rev = v * 0.15915494309189535f;
    rev -= floorf(rev);
    float s0 = __builtin_amdgcn_sinf(rev);
    float c0 = __builtin_amdgcn_cosf(rev);
    float s1 = 2.f * s0 * c0, c1 = c0 * c0 - s0 * s0;
    float s2 = 2.f * s1 * c1, c2 = c1 * c1 - s1 * s1;
    float s3 = 2.f * s2 * c2, c3 = c2 * c2 - s2 * s2;
    float s4 = 2.f * s3 * c3, c4 = c3 * c3 - s3 * s3;
    float s5 = 2.f * s4 * c4, c5 = c4 * c4 - s4 * s4;
    uint4 lo, hi;
    lo.x = pk(s0, v);  lo.y = pk(s2, s1);  lo.z = pk(s4, s3);  lo.w = pk(c0, s5);
    hi.x = pk(c2, c1); hi.y = pk(c4, c3);  hi.z = pk(0.f, c5); hi.w = 0u;
    *(uint4*)(dst)       = lo;
    *(uint4*)(dst + 128) = hi;
}

// W1 -> 15 slices, W2 -> 4 slices, W3 -> 4 mini B-frag slices (N padded 16);
// also zeroes the output (render waves 0/1 atomicAdd partials into it).
__global__ __launch_bounds__(256) void prep_kernel(
    const float* __restrict__ W1, const float* __restrict__ W2,
    const float* __restrict__ W3, u16* __restrict__ ws,
    float* __restrict__ out)
{
    int idx = blockIdx.x * 256 + threadIdx.x;
    if (idx < 12288) out[idx] = 0.f;                 // 4096 rays x 3
    if (idx < 61440) {                               // W1r: [ks15][nt8][lane64][j8]
        int j = idx & 7, lane = (idx >> 3) & 63, nt = (idx >> 9) & 7, ks = idx >> 12;
        int q = lane >> 4, l15 = lane & 15;
        int klocal = q * 8 + j;                      // 0..31
        int ch = ks * 2 + (klocal >> 4);
        int slot = klocal & 15;
        int n = nt * 16 + l15;
        ws[idx] = (slot < 13) ? f2bf(W1[orig_k(ch, slot) * 128 + n]) : (u16)0;
    } else if (idx < 77824) {                        // W2r: [ks4][nt8][lane64][j8]
        int i2 = idx - 61440;
        int j = i2 & 7, lane = (i2 >> 3) & 63, nt = (i2 >> 9) & 7, ks = i2 >> 12;
        int k = ks * 32 + (lane >> 4) * 8 + j;
        int n = nt * 16 + (lane & 15);
        ws[idx] = f2bf(W2[k * 128 + n]);
    } else if (idx < 79872) {                        // W3r: [ks4][lane64][j8], N pad 16
        int i3 = idx - 77824;
        int j = i3 & 7, lane = (i3 >> 3) & 63, ks = i3 >> 9;
        int k = ks * 32 + (lane >> 4) * 8 + j;
        int n = lane & 15;
        ws[idx] = (n < 3) ? f2bf(W3[k * 3 + n]) : (u16)0;
    }
}

// Load one slice's 2 B-frags (wave's 32-col strip) into named registers.
#define LOADB2(N0, N1, s)                                                     \
    if ((s) < NSLICE) {                                                       \
        const u16* wp = wp0 + (s) * 4096;                                     \
        N0 = *(const bf16x8*)(wp);                                            \
        N1 = *(const bf16x8*)(wp + 512);                                      \
    }

// One X-sourced K-slice: 4 A ds_reads (64-row strip, split 2+2) + 8 MFMA.
// Loads slice s+2's B-frags (3-pair rotation P,Q,R).
#define BODYX(s, C0,C1, N0,N1)                                                \
  {                                                                           \
    LOADB2(N0, N1, (s)+2);                                                    \
    const u16* ab = pool + ((s)&7)*4096 + (wm*256 + lane)*8;                  \
    bf16x8 a0 = *(const bf16x8*)(ab);                                         \
    bf16x8 a1 = *(const bf16x8*)(ab + 512);                                   \
    __builtin_amdgcn_s_setprio(1);                                            \
    acc[0][0]=MF(a0,C0,acc[0][0]); acc[0][1]=MF(a0,C1,acc[0][1]);             \
    acc[1][0]=MF(a1,C0,acc[1][0]); acc[1][1]=MF(a1,C1,acc[1][1]);             \
    a0 = *(const bf16x8*)(ab + 1024);                                         \
    a1 = *(const bf16x8*)(ab + 1536);                                         \
    acc[2][0]=MF(a0,C0,acc[2][0]); acc[2][1]=MF(a0,C1,acc[2][1]);             \
    acc[3][0]=MF(a1,C0,acc[3][0]); acc[3][1]=MF(a1,C1,acc[3][1]);             \
    __builtin_amdgcn_s_setprio(0);                                            \
  }

// First slice: C-in = 0 folded into the MFMA (no acc zero-init pass).
#define BODYX0(s, C0,C1, N0,N1)                                               \
  {                                                                           \
    LOADB2(N0, N1, (s)+2);                                                    \
    const u16* ab = pool + ((s)&7)*4096 + (wm*256 + lane)*8;                  \
    bf16x8 a0 = *(const bf16x8*)(ab);                                         \
    bf16x8 a1 = *(const bf16x8*)(ab + 512);                                   \
    __builtin_amdgcn_s_setprio(1);                                            \
    acc[0][0]=MF(a0,C0,vzero); acc[0][1]=MF(a0,C1,vzero);                     \
    acc[1][0]=MF(a1,C0,vzero); acc[1][1]=MF(a1,C1,vzero);                     \
    a0 = *(const bf16x8*)(ab + 1024);                                         \
    a1 = *(const bf16x8*)(ab + 1536);                                         \
    acc[2][0]=MF(a0,C0,vzero); acc[2][1]=MF(a0,C1,vzero);                     \
    acc[3][0]=MF(a1,C0,vzero); acc[3][1]=MF(a1,C1,vzero);                     \
    __builtin_amdgcn_s_setprio(0);                                            \
  }

// One h-sourced K-slice (GEMM2): A from swizzled h1 chunks (slots 0,1).
#define BODYH(s, C0,C1, N0,N1)                                                \
  {                                                                           \
    LOADB2(N0, N1, (s)+2);                                                    \
    int cb = ((((s)-15)*512) + wm*256 + lane) ^ quad;                         \
    bf16x8 a0 = *(const bf16x8*)(pool + cb*8);                                \
    bf16x8 a1 = *(const bf16x8*)(pool + (cb+64)*8);                           \
    __builtin_amdgcn_s_setprio(1);                                            \
    acc[0][0]=MF(a0,C0,acc[0][0]); acc[0][1]=MF(a0,C1,acc[0][1]);             \
    acc[1][0]=MF(a1,C0,acc[1][0]); acc[1][1]=MF(a1,C1,acc[1][1]);             \
    a0 = *(const bf16x8*)(pool + (cb+128)*8);                                 \
    a1 = *(const bf16x8*)(pool + (cb+192)*8);                                 \
    acc[2][0]=MF(a0,C0,acc[2][0]); acc[2][1]=MF(a0,C1,acc[2][1]);             \
    acc[3][0]=MF(a1,C0,acc[3][0]); acc[3][1]=MF(a1,C1,acc[3][1]);             \
    __builtin_amdgcn_s_setprio(0);                                            \
  }

// First GEMM2 slice: C-in = 0 folded in (no acc reset pass after epilogue 1).
#define BODYH0(s, C0,C1, N0,N1)                                               \
  {                                                                           \
    LOADB2(N0, N1, (s)+2);                                                    \
    int cb = ((((s)-15)*512) + wm*256 + lane) ^ quad;                         \
    bf16x8 a0 = *(const bf16x8*)(pool + cb*8);                                \
    bf16x8 a1 = *(const bf16x8*)(pool + (cb+64)*8);                           \
    __builtin_amdgcn_s_setprio(1);                                            \
    acc[0][0]=MF(a0,C0,vzero); acc[0][1]=MF(a0,C1,vzero);                     \
    acc[1][0]=MF(a1,C0,vzero); acc[1][1]=MF(a1,C1,vzero);                     \
    a0 = *(const bf16x8*)(pool + (cb+128)*8);                                 \
    a1 = *(const bf16x8*)(pool + (cb+192)*8);                                 \
    acc[2][0]=MF(a0,C0,vzero); acc[2][1]=MF(a0,C1,vzero);                     \
    acc[3][0]=MF(a1,C0,vzero); acc[3][1]=MF(a1,C1,vzero);                     \
    __builtin_amdgcn_s_setprio(0);                                            \
  }

// End of 2-group phase p: build groups 2p+2, 2p+3 into their slots, roll the
// 4-deep input prefetch (load groups 2p+6, 2p+7), single barrier.
#define GENDQ(p)                                                              \
  {                                                                           \
    if (8*(p)+8  + cl < 30)                                                   \
        build_x(pool + ((2*(p)+2)&3)*8192 + (cl>>1)*4096 + bxoff, pv_a);      \
    if (8*(p)+12 + cl < 30)                                                   \
        build_x(pool + ((2*(p)+3)&3)*8192 + (cl>>1)*4096 + bxoff, pv_b);      \
    pv_a = pv_c; pv_b = pv_d;                                                 \
    if (8*(p)+24 + cl < 30) pv_c = ldch(ap, vp, 8*(p)+24 + cl);               \
    if (8*(p)+28 + cl < 30) pv_d = ldch(ap, vp, 8*(p)+28 + cl);               \
    BAR();                                                                    \
  }

// Vectorized epilogue store: packed add/max + paired bf16 cvt, 4 u16 writes.
#define EPI4(OFS, ACC, BB, rwb, col)                                          \
  { f32x4 t_ = ACC + BB;                                                      \
    t_ = __builtin_elementwise_max(t_, vzero);                                \
    unsigned w01_ = pk(t_[1], t_[0]);                                         \
    unsigned w23_ = pk(t_[3], t_[2]);                                         \
    pool[(OFS) + afoff_h((rwb) + 0, col)] = (u16)w01_;                        \
    pool[(OFS) + afoff_h((rwb) + 1, col)] = (u16)(w01_ >> 16);                \
    pool[(OFS) + afoff_h((rwb) + 2, col)] = (u16)w23_;                        \
    pool[(OFS) + afoff_h((rwb) + 3, col)] = (u16)(w23_ >> 16); }

// 8 waves: wave (wm = wave>>2, wn = wave&3) owns a 64x32 output tile
// (A-amp 4 via LDS, B-amp 2 via L1/L2 registers). 7 lgkm-only barriers.
__global__ __launch_bounds__(512, 4) void render_kernel(
    const float* __restrict__ sigma_g, const float* __restrict__ app_g,
    const float* __restrict__ view_g,  const float* __restrict__ dists_g,
    const float* __restrict__ b1_g,    const float* __restrict__ b2_g,
    const float* __restrict__ b3_g,    const u16* __restrict__ ws,
    float* __restrict__ out_g)
{
    __shared__ __align__(16) u16 pool[POOLSZ];
    __shared__ __align__(16) float part[NS * 3];
    __shared__ float scanS;          // wave0 scan total broadcast

    const int tid  = threadIdx.x;
    const int lane = tid & 63;
    const int wave = tid >> 6;       // 0..7
    const int l15  = lane & 15;
    const int quad = lane >> 4;
    const int wm   = wave >> 2;      // row half (64 rows)
    const int wn   = wave & 3;       // col quarter (32 cols)

    const int r  = blockIdx.x;
    const int rb = r * NS;
    const int row = tid & 127;       // X-build row (all 512 threads build)
    const int cl  = tid >> 7;        // X-build channel-local 0..3 (2 slices)
    const float* ap = app_g  + (rb + row) * 27;
    const float* vp = view_g + (rb + row) * 3;
    // hoisted per-thread build offset within a slice
    const int bxoff = (row >> 4) * 512 + (((cl & 1) * 32) + (row & 15)) * 8;

    // issue B loads for slices 0,1 ASAP (3-pair rotation P,Q,R)
    const u16* wp0 = ws + (wn * 128 + lane) * 8;
    bf16x8 bP0, bP1, bQ0, bQ1, bR0, bR1;
    LOADB2(bP0, bP1, 0);
    LOADB2(bQ0, bQ1, 1);

    // rolling input prefetch (4 resident: groups g..g+3's channel values)
    float pv_a = ldch(ap, vp, cl);           // g0
    float pv_b = ldch(ap, vp, 4 + cl);       // g1
    float pv_c = ldch(ap, vp, 8 + cl);       // g2
    float pv_d = ldch(ap, vp, 12 + cl);      // g3

    // ---- alpha + shuffle transmittance scan (waves 0,1) ----
    float alpha = 0.f, prod = 1.f, wr = 0.f;
    if (tid < NS) {
        float x  = sigma_g[rb + tid] - 10.f;
        float sp = (x > 20.f) ? x : log1pf(expf(x));
        alpha = 1.f - expf(-sp * dists_g[rb + tid] * 25.f);
        if (tid == NS - 1) alpha = 1.f;
        float tb = 1.f - alpha + 1e-10f;
        prod = tb;
        #pragma unroll
        for (int d = 1; d < 64; d <<= 1) {
            float v = __shfl_up(prod, d);
            if (lane >= d) prod *= v;
        }
        if (tid == 63) scanS = prod;
    }

    // ---- pre-build X groups 0,1 (slices 0..3) into slots 0,1 ----
    build_x(pool +        (cl >> 1) * 4096 + bxoff, pv_a);
    build_x(pool + 8192 + (cl >> 1) * 4096 + bxoff, pv_b);
    pv_a = pv_c; pv_b = pv_d;
    pv_c = ldch(ap, vp, 16 + cl);            // g4
    pv_d = ldch(ap, vp, 20 + cl);            // g5
    BAR();

    // finish weights: wr = alpha * T_exclusive
    if (tid < NS) {
        float prev = __shfl_up(prod, 1);
        float base = (lane == 0) ? 1.f : prev;
        float scale = (wave == 1) ? scanS : 1.f;
        wr = alpha * base * scale;
    }

    const f32x4 vzero = {0.f, 0.f, 0.f, 0.f};
    f32x4 acc[4][2];

    // ---- GEMM1: slices 0..14, 4-slice phases (pair s%3: 0=P 1=Q 2=R) ----
    BODYX0(0, bP0,bP1, bR0,bR1);              // C=0 folded: no acc init pass
    BODYX(1,  bQ0,bQ1, bP0,bP1);
    BODYX(2,  bR0,bR1, bQ0,bQ1);
    BODYX(3,  bP0,bP1, bR0,bR1);  GENDQ(0);   // builds g2,g3 (slices 4..7)
    BODYX(4,  bQ0,bQ1, bP0,bP1);
    BODYX(5,  bR0,bR1, bQ0,bQ1);
    BODYX(6,  bP0,bP1, bR0,bR1);
    BODYX(7,  bQ0,bQ1, bP0,bP1);  GENDQ(1);   // builds g4,g5 (slices 8..11)
    BODYX(8,  bR0,bR1, bQ0,bQ1);
    BODYX(9,  bP0,bP1, bR0,bR1);
    BODYX(10, bQ0,bQ1, bP0,bP1);
    BODYX(11, bR0,bR1, bQ0,bQ1);  GENDQ(2);   // builds g6,g7 (slices 12..14)
    // b1 issued here so its latency hides under the last GEMM1 phase
    const float b1r0 = b1_g[wn * 32 + l15];
    const float b1r1 = b1_g[wn * 32 + 16 + l15];
    BODYX(12, bP0,bP1, bR0,bR1);
    BODYX(13, bQ0,bQ1, bP0,bP1);              // loads slice 15 -> P
    BODYX(14, bR0,bR1, bQ0,bQ1);              // loads slice 16 -> Q

    // ---- epilogue 1 (NO pre-barrier): h1 -> slots 0,1; concurrent
    // slice-12..14 reads live in slots 2,3 (disjoint). ----
    {
        const f32x4 bb0 = {b1r0, b1r0, b1r0, b1r0};
        const f32x4 bb1 = {b1r1, b1r1, b1r1, b1r1};
        #pragma unroll
        for (int mt = 0; mt < 4; ++mt) {
            int rwb = wm * 64 + mt * 16 + quad * 4;
            EPI4(0, acc[mt][0], bb0, rwb, wn * 32 + l15);
            EPI4(0, acc[mt][1], bb1, rwb, wn * 32 + 16 + l15);
        }
    }
    BAR();   // h1 visible to all waves AND slot-2,3 reads drained

    const float b2r0 = b2_g[wn * 32 + l15];
    const float b2r1 = b2_g[wn * 32 + 16 + l15];

    // ---- GEMM2: slices 15..18 (h1 @ W2), barrier-free run ----
    BODYH0(15, bP0,bP1, bR0,bR1);             // C=0 folded; loads 17 -> R
    BODYH(16, bQ0,bQ1, bP0,bP1);              // loads slice 18 -> P
    BODYH(17, bR0,bR1, bQ0,bQ1);
    BODYH(18, bP0,bP1, bR0,bR1);

    // ---- epilogue 2 (NO pre-barrier): h2 -> slots 2,3; concurrent GEMM2
    // reads live in slots 0,1 (disjoint); old slot-2,3 readers drained. ----
    {
        const f32x4 bb0 = {b2r0, b2r0, b2r0, b2r0};
        const f32x4 bb1 = {b2r1, b2r1, b2r1, b2r1};
        #pragma unroll
        for (int mt = 0; mt < 4; ++mt) {
            int rwb = wm * 64 + mt * 16 + quad * 4;
            EPI4(OH2, acc[mt][0], bb0, rwb, wn * 32 + l15);
            EPI4(OH2, acc[mt][1], bb1, rwb, wn * 32 + 16 + l15);
        }
    }
    BAR();   // h2 visible

    // ---- layer 3 via MFMA: rgb = sigmoid(h2 @ W3 + b3); wave = row-tile ----
    const u16* w3r = ws + 77824;
    const float b3v = (l15 < 3) ? b3_g[l15] : 0.f;
    f32x4 acc3 = vzero;
    #pragma unroll
    for (int ks = 0; ks < 4; ++ks) {
        bf16x8 w3f = *(const bf16x8*)(w3r + (ks * 64 + lane) * 8);
        int c = ((ks * 8 + wave) * 64 + lane) ^ quad;
        bf16x8 a3 = *(const bf16x8*)(pool + OH2 + c * 8);
        acc3 = MF(a3, w3f, acc3);
    }
    if (l15 < 3) {
        #pragma unroll
        for (int rr = 0; rr < 4; ++rr) {
            int rw = wave * 16 + quad * 4 + rr;
            float v = acc3[rr] + b3v;
            part[rw * 3 + l15] = 1.f / (1.f + expf(-v));
        }
    }
    BAR();

    // ---- weighted sum over samples; waves 0,1 atomicAdd their partials
    // (out zeroed by prep; 2 addends commutative -> bit-exact) ----
    if (tid < NS) {
        float v0 = wr * part[tid * 3 + 0];
        float v1 = wr * part[tid * 3 + 1];
        float v2 = wr * part[tid * 3 + 2];
        #pragma unroll
        for (int d = 1; d < 64; d <<= 1) {
            v0 += __shfl_xor(v0, d);
            v1 += __shfl_xor(v1, d);
            v2 += __shfl_xor(v2, d);
        }
        if (lane == 0) {
            atomicAdd(&out_g[r * 3 + 0], v0);
            atomicAdd(&out_g[r * 3 + 1], v1);
            atomicAdd(&out_g[r * 3 + 2], v2);
        }
    }
}

extern "C" void kernel_launch(void* const* d_in, const int* in_sizes, int n_in,
                              void* d_out, int out_size, void* d_ws, size_t ws_size,
                              hipStream_t stream) {
    (void)in_sizes; (void)n_in; (void)out_size; (void)ws_size;
    const float* sigma = (const float*)d_in[0];
    const float* app   = (const float*)d_in[1];
    const float* view  = (const float*)d_in[2];
    const float* dists = (const float*)d_in[3];
    const float* W1    = (const float*)d_in[4];
    const float* b1    = (const float*)d_in[5];
    const float* W2    = (const float*)d_in[6];
    const float* b2    = (const float*)d_in[7];
    const float* W3    = (const float*)d_in[8];
    const float* b3    = (const float*)d_in[9];
    float* out = (float*)d_out;

    u16* ws = (u16*)d_ws;   // 61440 (W1r) + 16384 (W2r) + 2048 (W3r) u16 = 159744 B

    prep_kernel<<<312, 256, 0, stream>>>(W1, W2, W3, ws, out);
    render_kernel<<<NBLOCKS, 512, 0, stream>>>(sigma, app, view, dists,
                                               b1, b2, b3, ws, out);
}

// Round 12
// 193.970 us; speedup vs baseline: 1.4434x; 1.0121x over previous
//
#include <hip/hip_runtime.h>
#include <math.h>

typedef unsigned short u16;
using bf16x8 = __attribute__((ext_vector_type(8))) short;
using f32x4  = __attribute__((ext_vector_type(4))) float;

#define NS      128
#define NBLOCKS 4096    // 1 ray per block, 512 threads (8 waves)
#define NSLICE  19      // 15 (W1) + 4 (W2) unified W slices of 4096 u16
#define OWGT    81920   // u16 offset of fp32 weight table (4096x128 f32, 2 MB)

// LDS pool (u16): X QUAD-buffer = 4 group slots x 8192 u16 = 64 KB.
// Slice s lives at (s&7)*4096. h1 overlays slots 0,1 (u16 0..16384);
// h2 overlays slots 2,3 (16384..32768) -> epilogue writes never race live
// readers, so no read-drain barriers. 6 barriers/ray total.
#define POOLSZ 32768
#define OH2    16384

// Raw barrier: drain LDS only; global register-prefetches stay in flight.
#define BAR() do { asm volatile("s_waitcnt lgkmcnt(0)" ::: "memory");        \
                   __builtin_amdgcn_s_barrier();                              \
                   asm volatile("" ::: "memory"); } while (0)

#define MF(A,B,C) __builtin_amdgcn_mfma_f32_16x16x32_bf16((A),(B),(C),0,0,0)

__device__ __forceinline__ u16 f2bf(float f) {           // host-prep path only
    unsigned int i = __float_as_uint(f);
    return (u16)((i + 0x7FFFu + ((i >> 16) & 1u)) >> 16);  // RNE
}

// pack two floats to bf16 pair [hi:lo] in one dword (single VALU op, RNE)
__device__ __forceinline__ unsigned pk(float hi, float lo) {
    unsigned r;
    asm("v_cvt_pk_bf16_f32 %0, %1, %2" : "=v"(r) : "v"(lo), "v"(hi));
    return r;
}

// Swizzled A-frag-order offset for a h [128x128] region: XOR (k>>3)&3 into
// the chunk index (readers apply chunk^quad) to spread the epilogue's
// column-wise u16 writes across more banks.
__device__ __forceinline__ int afoff_h(int m, int k) {
    int chunk = ((k >> 5) * 8 + (m >> 4)) * 64 + ((k >> 3) & 3) * 16 + (m & 15);
    chunk ^= (k >> 3) & 3;
    return chunk * 8 + (k & 7);
}

// channel/slot -> original mlp_in k index (reference ordering)
__device__ __forceinline__ int orig_k(int ch, int slot) {
    if (ch < 27) {
        if (slot == 0) return ch;
        if (slot <= 6) return 30 + ch * 6 + (slot - 1);     // sin(app)
        return 192 + ch * 6 + (slot - 7);                    // cos(app)
    } else {
        int c = ch - 27;
        if (slot == 0) return 27 + c;
        if (slot <= 6) return 354 + c * 6 + (slot - 1);      // sin(view)
        return 372 + c * 6 + (slot - 7);                     // cos(view)
    }
}

__device__ __forceinline__ float ldch(const float* ap, const float* vp, int c) {
    return (c < 27) ? ap[c] : vp[c - 27];
}

// build one channel-half of a frag-order X slice at a precomputed dst:
// slots [v, sin f0..5, cos f0..5, 0 x3] as two 16B chunks (dst, dst+128).
__device__ __forceinline__ void build_x(u16* dst, float v) {
    float rev = v * 0.15915494309189535f;
    rev -= floorf(rev);
    float s0 = __builtin_amdgcn_sinf(rev);
    float c0 = __builtin_amdgcn_cosf(rev);
    float s1 = 2.f * s0 * c0, c1 = c0 * c0 - s0 * s0;
    float s2 = 2.f * s1 * c1, c2 = c1 * c1 - s1 * s1;
    float s3 = 2.f * s2 * c2, c3 = c2 * c2 - s2 * s2;
    float s4 = 2.f * s3 * c3, c4 = c3 * c3 - s3 * s3;
    float s5 = 2.f * s4 * c4, c5 = c4 * c4 - s4 * s4;
    uint4 lo, hi;
    lo.x = pk(s0, v);  lo.y = pk(s2, s1);  lo.z = pk(s4, s3);  lo.w = pk(c0, s5);
    hi.x = pk(c2, c1); hi.y = pk(c4, c3);  hi.z = pk(0.f, c5); hi.w = 0u;
    *(uint4*)(dst)       = lo;
    *(uint4*)(dst + 128) = hi;
}

// W1 -> 15 slices, W2 -> 4 slices, W3 -> 4 mini B-frag slices (N padded 16);
// zeroes the output; computes per-ray transmittance weights (one wave/ray,
// identical shuffle-scan math to the old render path -> bit-exact).
__global__ __launch_bounds__(256) void prep_kernel(
    const float* __restrict__ W1, const float* __restrict__ W2,
    const float* __restrict__ W3, const float* __restrict__ sigma_g,
    const float* __restrict__ dists_g, u16* __restrict__ ws,
    float* __restrict__ out)
{
    int idx = blockIdx.x * 256 + threadIdx.x;
    if (idx < 12288) out[idx] = 0.f;                 // 4096 rays x 3
    if (idx < 61440) {                               // W1r: [ks15][nt8][lane64][j8]
        int j = idx & 7, lane = (idx >> 3) & 63, nt = (idx >> 9) & 7, ks = idx >> 12;
        int q = lane >> 4, l15 = lane & 15;
        int klocal = q * 8 + j;                      // 0..31
        int ch = ks * 2 + (klocal >> 4);
        int slot = klocal & 15;
        int n = nt * 16 + l15;
        ws[idx] = (slot < 13) ? f2bf(W1[orig_k(ch, slot) * 128 + n]) : (u16)0;
    } else if (idx < 77824) {                        // W2r: [ks4][nt8][lane64][j8]
        int i2 = idx - 61440;
        int j = i2 & 7, lane = (i2 >> 3) & 63, nt = (i2 >> 9) & 7, ks = i2 >> 12;
        int k = ks * 32 + (lane >> 4) * 8 + j;
        int n = nt * 16 + (lane & 15);
        ws[idx] = f2bf(W2[k * 128 + n]);
    } else if (idx < 79872) {                        // W3r: [ks4][lane64][j8], N pad 16
        int i3 = idx - 77824;
        int j = i3 & 7, lane = (i3 >> 3) & 63, ks = i3 >> 9;
        int k = ks * 32 + (lane >> 4) * 8 + j;
        int n = lane & 15;
        ws[idx] = (n < 3) ? f2bf(W3[k * 3 + n]) : (u16)0;
    }
    // ---- weights: wave (idx>>6) owns ray (idx>>6); lane ln handles samples
    // ln and ln+64 (same op sequence as the old two-wave render scan). ----
    {
        int ray = idx >> 6, ln = idx & 63;           // 1024 blocks x 4 waves = 4096
        float* wgt = (float*)(ws + OWGT);
        int base = ray * NS;
        float x0 = sigma_g[base + ln] - 10.f;
        float sp0 = (x0 > 20.f) ? x0 : log1pf(expf(x0));
        float a0 = 1.f - expf(-sp0 * dists_g[base + ln] * 25.f);
        float x1 = sigma_g[base + 64 + ln] - 10.f;
        float sp1 = (x1 > 20.f) ? x1 : log1pf(expf(x1));
        float a1 = 1.f - expf(-sp1 * dists_g[base + 64 + ln] * 25.f);
        if (ln == 63) a1 = 1.f;                      // last sample forced opaque
        float p0 = 1.f - a0 + 1e-10f;
        float p1 = 1.f - a1 + 1e-10f;
        #pragma unroll
        for (int d = 1; d < 64; d <<= 1) {
            float v0 = __shfl_up(p0, d);
            float v1 = __shfl_up(p1, d);
            if (ln >= d) { p0 *= v0; p1 *= v1; }
        }
        float S0 = __shfl(p0, 63);                   // first-half total
        float q0 = __shfl_up(p0, 1);
        float q1 = __shfl_up(p1, 1);
        wgt[base + ln]      = a0 * ((ln == 0) ? 1.f : q0);
        wgt[base + 64 + ln] = a1 * ((ln == 0) ? 1.f : q1) * S0;
    }
}

// Load one slice's 2 B-frags (wave's 32-col strip) into named registers.
#define LOADB2(N0, N1, s)                                                     \
    if ((s) < NSLICE) {                                                       \
        const u16* wp = wp0 + (s) * 4096;                                     \
        N0 = *(const bf16x8*)(wp);                                            \
        N1 = *(const bf16x8*)(wp + 512);                                      \
    }

// One X-sourced K-slice: 4 A ds_reads (64-row strip, split 2+2) + 8 MFMA.
// Loads slice s+2's B-frags (3-pair rotation P,Q,R).
#define BODYX(s, C0,C1, N0,N1)                                                \
  {                                                                           \
    LOADB2(N0, N1, (s)+2);                                                    \
    const u16* ab = pool + ((s)&7)*4096 + (wm*256 + lane)*8;                  \
    bf16x8 a0 = *(const bf16x8*)(ab);                                         \
    bf16x8 a1 = *(const bf16x8*)(ab + 512);                                   \
    __builtin_amdgcn_s_setprio(1);                                            \
    acc[0][0]=MF(a0,C0,acc[0][0]); acc[0][1]=MF(a0,C1,acc[0][1]);             \
    acc[1][0]=MF(a1,C0,acc[1][0]); acc[1][1]=MF(a1,C1,acc[1][1]);             \
    a0 = *(const bf16x8*)(ab + 1024);                                         \
    a1 = *(const bf16x8*)(ab + 1536);                                         \
    acc[2][0]=MF(a0,C0,acc[2][0]); acc[2][1]=MF(a0,C1,acc[2][1]);             \
    acc[3][0]=MF(a1,C0,acc[3][0]); acc[3][1]=MF(a1,C1,acc[3][1]);             \
    __builtin_amdgcn_s_setprio(0);                                            \
  }

// First slice: C-in = 0 folded into the MFMA (no acc zero-init pass).
#define BODYX0(s, C0,C1, N0,N1)                                               \
  {                                                                           \
    LOADB2(N0, N1, (s)+2);                                                    \
    const u16* ab = pool + ((s)&7)*4096 + (wm*256 + lane)*8;                  \
    bf16x8 a0 = *(const bf16x8*)(ab);                                         \
    bf16x8 a1 = *(const bf16x8*)(ab + 512);                                   \
    __builtin_amdgcn_s_setprio(1);                                            \
    acc[0][0]=MF(a0,C0,vzero); acc[0][1]=MF(a0,C1,vzero);                     \
    acc[1][0]=MF(a1,C0,vzero); acc[1][1]=MF(a1,C1,vzero);                     \
    a0 = *(const bf16x8*)(ab + 1024);                                         \
    a1 = *(const bf16x8*)(ab + 1536);                                         \
    acc[2][0]=MF(a0,C0,vzero); acc[2][1]=MF(a0,C1,vzero);                     \
    acc[3][0]=MF(a1,C0,vzero); acc[3][1]=MF(a1,C1,vzero);                     \
    __builtin_amdgcn_s_setprio(0);                                            \
  }

// One h-sourced K-slice (GEMM2): A from swizzled h1 chunks (slots 0,1).
#define BODYH(s, C0,C1, N0,N1)                                                \
  {                                                                           \
    LOADB2(N0, N1, (s)+2);                                                    \
    int cb = ((((s)-15)*512) + wm*256 + lane) ^ quad;                         \
    bf16x8 a0 = *(const bf16x8*)(pool + cb*8);                                \
    bf16x8 a1 = *(const bf16x8*)(pool + (cb+64)*8);                           \
    __builtin_amdgcn_s_setprio(1);                                            \
    acc[0][0]=MF(a0,C0,acc[0][0]); acc[0][1]=MF(a0,C1,acc[0][1]);             \
    acc[1][0]=MF(a1,C0,acc[1][0]); acc[1][1]=MF(a1,C1,acc[1][1]);             \
    a0 = *(const bf16x8*)(pool + (cb+128)*8);                                 \
    a1 = *(const bf16x8*)(pool + (cb+192)*8);                                 \
    acc[2][0]=MF(a0,C0,acc[2][0]); acc[2][1]=MF(a0,C1,acc[2][1]);             \
    acc[3][0]=MF(a1,C0,acc[3][0]); acc[3][1]=MF(a1,C1,acc[3][1]);             \
    __builtin_amdgcn_s_setprio(0);                                            \
  }

// First GEMM2 slice: C-in = 0 folded in (no acc reset pass after epilogue 1).
#define BODYH0(s, C0,C1, N0,N1)                                               \
  {                                                                           \
    LOADB2(N0, N1, (s)+2);                                                    \
    int cb = ((((s)-15)*512) + wm*256 + lane) ^ quad;                         \
    bf16x8 a0 = *(const bf16x8*)(pool + cb*8);                                \
    bf16x8 a1 = *(const bf16x8*)(pool + (cb+64)*8);                           \
    __builtin_amdgcn_s_setprio(1);                                            \
    acc[0][0]=MF(a0,C0,vzero); acc[0][1]=MF(a0,C1,vzero);                     \
    acc[1][0]=MF(a1,C0,vzero); acc[1][1]=MF(a1,C1,vzero);                     \
    a0 = *(const bf16x8*)(pool + (cb+128)*8);                                 \
    a1 = *(const bf16x8*)(pool + (cb+192)*8);                                 \
    acc[2][0]=MF(a0,C0,vzero); acc[2][1]=MF(a0,C1,vzero);                     \
    acc[3][0]=MF(a1,C0,vzero); acc[3][1]=MF(a1,C1,vzero);                     \
    __builtin_amdgcn_s_setprio(0);                                            \
  }

// End of 2-group phase p: build groups 2p+2, 2p+3 into their slots, roll the
// 4-deep input prefetch (load groups 2p+6, 2p+7), single barrier.
#define GENDQ(p)                                                              \
  {                                                                           \
    if (8*(p)+8  + cl < 30)                                                   \
        build_x(pool + ((2*(p)+2)&3)*8192 + (cl>>1)*4096 + bxoff, pv_a);      \
    if (8*(p)+12 + cl < 30)                                                   \
        build_x(pool + ((2*(p)+3)&3)*8192 + (cl>>1)*4096 + bxoff, pv_b);      \
    pv_a = pv_c; pv_b = pv_d;                                                 \
    if (8*(p)+24 + cl < 30) pv_c = ldch(ap, vp, 8*(p)+24 + cl);               \
    if (8*(p)+28 + cl < 30) pv_d = ldch(ap, vp, 8*(p)+28 + cl);               \
    BAR();                                                                    \
  }

// Vectorized epilogue store: packed add/max + paired bf16 cvt, 4 u16 writes.
#define EPI4(OFS, ACC, BB, rwb, col)                                          \
  { f32x4 t_ = ACC + BB;                                                      \
    t_ = __builtin_elementwise_max(t_, vzero);                                \
    unsigned w01_ = pk(t_[1], t_[0]);                                         \
    unsigned w23_ = pk(t_[3], t_[2]);                                         \
    pool[(OFS) + afoff_h((rwb) + 0, col)] = (u16)w01_;                        \
    pool[(OFS) + afoff_h((rwb) + 1, col)] = (u16)(w01_ >> 16);                \
    pool[(OFS) + afoff_h((rwb) + 2, col)] = (u16)w23_;                        \
    pool[(OFS) + afoff_h((rwb) + 3, col)] = (u16)(w23_ >> 16); }

// 8 waves: wave (wm = wave>>2, wn = wave&3) owns a 64x32 output tile
// (A-amp 4 via LDS, B-amp 2 via L1/L2 registers). 6 lgkm-only barriers.
// Head: no scan (weights precomputed in prep); tail: direct weighted
// reduction with float4 weight loads, no part buffer, no final barrier.
__global__ __launch_bounds__(512, 4) void render_kernel(
    const float* __restrict__ app_g,   const float* __restrict__ view_g,
    const float* __restrict__ b1_g,    const float* __restrict__ b2_g,
    const float* __restrict__ b3_g,    const u16* __restrict__ ws,
    float* __restrict__ out_g)
{
    __shared__ __align__(16) u16 pool[POOLSZ];

    const int tid  = threadIdx.x;
    const int lane = tid & 63;
    const int wave = tid >> 6;       // 0..7
    const int l15  = lane & 15;
    const int quad = lane >> 4;
    const int wm   = wave >> 2;      // row half (64 rows)
    const int wn   = wave & 3;       // col quarter (32 cols)

    const int r  = blockIdx.x;
    const int rb = r * NS;
    const int row = tid & 127;       // X-build row (all 512 threads build)
    const int cl  = tid >> 7;        // X-build channel-local 0..3 (2 slices)
    const float* ap = app_g  + (rb + row) * 27;
    const float* vp = view_g + (rb + row) * 3;
    // hoisted per-thread build offset within a slice
    const int bxoff = (row >> 4) * 512 + (((cl & 1) * 32) + (row & 15)) * 8;

    // issue B loads for slices 0,1 ASAP (3-pair rotation P,Q,R)
    const u16* wp0 = ws + (wn * 128 + lane) * 8;
    bf16x8 bP0, bP1, bQ0, bQ1, bR0, bR1;
    LOADB2(bP0, bP1, 0);
    LOADB2(bQ0, bQ1, 1);

    // rolling input prefetch (4 resident: groups g..g+3's channel values)
    float pv_a = ldch(ap, vp, cl);           // g0
    float pv_b = ldch(ap, vp, 4 + cl);       // g1
    float pv_c = ldch(ap, vp, 8 + cl);       // g2
    float pv_d = ldch(ap, vp, 12 + cl);      // g3

    // ---- pre-build X groups 0,1 (slices 0..3) into slots 0,1 ----
    build_x(pool +        (cl >> 1) * 4096 + bxoff, pv_a);
    build_x(pool + 8192 + (cl >> 1) * 4096 + bxoff, pv_b);
    pv_a = pv_c; pv_b = pv_d;
    pv_c = ldch(ap, vp, 16 + cl);            // g4
    pv_d = ldch(ap, vp, 20 + cl);            // g5
    BAR();

    const f32x4 vzero = {0.f, 0.f, 0.f, 0.f};
    f32x4 acc[4][2];

    // ---- GEMM1: slices 0..14, 4-slice phases (pair s%3: 0=P 1=Q 2=R) ----
    BODYX0(0, bP0,bP1, bR0,bR1);              // C=0 folded: no acc init pass
    BODYX(1,  bQ0,bQ1, bP0,bP1);
    BODYX(2,  bR0,bR1, bQ0,bQ1);
    BODYX(3,  bP0,bP1, bR0,bR1);  GENDQ(0);   // builds g2,g3 (slices 4..7)
    BODYX(4,  bQ0,bQ1, bP0,bP1);
    BODYX(5,  bR0,bR1, bQ0,bQ1);
    BODYX(6,  bP0,bP1, bR0,bR1);
    BODYX(7,  bQ0,bQ1, bP0,bP1);  GENDQ(1);   // builds g4,g5 (slices 8..11)
    BODYX(8,  bR0,bR1, bQ0,bQ1);
    BODYX(9,  bP0,bP1, bR0,bR1);
    BODYX(10, bQ0,bQ1, bP0,bP1);
    BODYX(11, bR0,bR1, bQ0,bQ1);  GENDQ(2);   // builds g6,g7 (slices 12..14)
    // b1 issued here so its latency hides under the last GEMM1 phase
    const float b1r0 = b1_g[wn * 32 + l15];
    const float b1r1 = b1_g[wn * 32 + 16 + l15];
    BODYX(12, bP0,bP1, bR0,bR1);
    BODYX(13, bQ0,bQ1, bP0,bP1);              // loads slice 15 -> P
    BODYX(14, bR0,bR1, bQ0,bQ1);              // loads slice 16 -> Q

    // ---- epilogue 1 (NO pre-barrier): h1 -> slots 0,1; concurrent
    // slice-12..14 reads live in slots 2,3 (disjoint). ----
    {
        const f32x4 bb0 = {b1r0, b1r0, b1r0, b1r0};
        const f32x4 bb1 = {b1r1, b1r1, b1r1, b1r1};
        #pragma unroll
        for (int mt = 0; mt < 4; ++mt) {
            int rwb = wm * 64 + mt * 16 + quad * 4;
            EPI4(0, acc[mt][0], bb0, rwb, wn * 32 + l15);
            EPI4(0, acc[mt][1], bb1, rwb, wn * 32 + 16 + l15);
        }
    }
    BAR();   // h1 visible to all waves AND slot-2,3 reads drained

    const float b2r0 = b2_g[wn * 32 + l15];
    const float b2r1 = b2_g[wn * 32 + 16 + l15];

    // ---- GEMM2: slices 15..18 (h1 @ W2), barrier-free run ----
    BODYH0(15, bP0,bP1, bR0,bR1);             // C=0 folded; loads 17 -> R
    BODYH(16, bQ0,bQ1, bP0,bP1);              // loads slice 18 -> P
    BODYH(17, bR0,bR1, bQ0,bQ1);
    BODYH(18, bP0,bP1, bR0,bR1);

    // ---- epilogue 2 (NO pre-barrier): h2 -> slots 2,3; concurrent GEMM2
    // reads live in slots 0,1 (disjoint); old slot-2,3 readers drained. ----
    {
        const f32x4 bb0 = {b2r0, b2r0, b2r0, b2r0};
        const f32x4 bb1 = {b2r1, b2r1, b2r1, b2r1};
        #pragma unroll
        for (int mt = 0; mt < 4; ++mt) {
            int rwb = wm * 64 + mt * 16 + quad * 4;
            EPI4(OH2, acc[mt][0], bb0, rwb, wn * 32 + l15);
            EPI4(OH2, acc[mt][1], bb1, rwb, wn * 32 + 16 + l15);
        }
    }
    BAR();   // h2 visible

    // ---- layer 3 via MFMA + direct weighted reduction (no part, no BAR) ----
    const u16* w3r = ws + 77824;
    // issue the weight load first so it flies under the MFMAs
    const float4 w4 = *(const float4*)((const float*)(ws + OWGT)
                                       + rb + wave * 16 + quad * 4);
    const float b3v = (l15 < 3) ? b3_g[l15] : 0.f;
    f32x4 acc3 = vzero;
    #pragma unroll
    for (int ks = 0; ks < 4; ++ks) {
        bf16x8 w3f = *(const bf16x8*)(w3r + (ks * 64 + lane) * 8);
        int c = ((ks * 8 + wave) * 64 + lane) ^ quad;
        bf16x8 a3 = *(const bf16x8*)(pool + OH2 + c * 8);
        acc3 = MF(a3, w3f, acc3);
    }
    float v = 0.f;
    if (l15 < 3) {
        v  = w4.x / (1.f + expf(-(acc3[0] + b3v)));
        v += w4.y / (1.f + expf(-(acc3[1] + b3v)));
        v += w4.z / (1.f + expf(-(acc3[2] + b3v)));
        v += w4.w / (1.f + expf(-(acc3[3] + b3v)));
    }
    v += __shfl_xor(v, 16);      // sum the 4 quads (rows) of this wave
    v += __shfl_xor(v, 32);
    if (lane < 3)                // out zeroed by prep; 8 wave-partials/color
        atomicAdd(&out_g[r * 3 + lane], v);
}

extern "C" void kernel_launch(void* const* d_in, const int* in_sizes, int n_in,
                              void* d_out, int out_size, void* d_ws, size_t ws_size,
                              hipStream_t stream) {
    (void)in_sizes; (void)n_in; (void)out_size; (void)ws_size;
    const float* sigma = (const float*)d_in[0];
    const float* app   = (const float*)d_in[1];
    const float* view  = (const float*)d_in[2];
    const float* dists = (const float*)d_in[3];
    const float* W1    = (const float*)d_in[4];
    const float* b1    = (const float*)d_in[5];
    const float* W2    = (const float*)d_in[6];
    const float* b2    = (const float*)d_in[7];
    const float* W3    = (const float*)d_in[8];
    const float* b3    = (const float*)d_in[9];
    float* out = (float*)d_out;

    u16* ws = (u16*)d_ws;   // 159744 B frag tables + 2 MB fp32 weights @ OWGT

    prep_kernel<<<1024, 256, 0, stream>>>(W1, W2, W3, sigma, dists, ws, out);
    render_kernel<<<NBLOCKS, 512, 0, stream>>>(app, view, b1, b2, b3, ws, out);
}